// Round 10
// baseline (313.723 us; speedup 1.0000x reference)
//
#include <hip/hip_runtime.h>
#include <hip/hip_bf16.h>

#define IN_C 512
#define OUT_C 256
#define NN 8192
#define KSPL 4
#define KRANGE (NN / KSPL)       // 2048
#define L2E 1.44269504088896f

typedef __attribute__((ext_vector_type(8))) short s16x8;
typedef __attribute__((ext_vector_type(4))) float f32x4;
typedef __attribute__((ext_vector_type(4))) int i32x4;
typedef __attribute__((ext_vector_type(2))) unsigned int u32x2;

__device__ __forceinline__ ushort f2bf(float f) {
    unsigned u = __float_as_uint(f);
    unsigned r = (u + 0x7FFF + ((u >> 16) & 1)) >> 16;
    return (ushort)r;
}

// ---------------- Kernel A: h = x@W_fc + b_fc (fp32); store h bf16 in k-chunk-major
// tiles: hb[jt32][u][col] (uint4 = 8 bf16, k = jt32*32 + u*8 + e), u=0..3.
// Also s1 = h@Wa1+ba1, s2 = h@Wa2+ba2 ----------------
__global__ __launch_bounds__(256) void fc_kernel(
    const float* __restrict__ x, const float* __restrict__ Wfc,
    const float* __restrict__ bfc, const float* __restrict__ Wa1,
    const float* __restrict__ ba1, const float* __restrict__ Wa2,
    const float* __restrict__ ba2,
    uint4* __restrict__ hb,     // [NN/32][4][256] uint4
    float* __restrict__ s1, float* __restrict__ s2)
{
    __shared__ float xl[8 * IN_C];          // 16 KB
    __shared__ float red[2][8][4];
    const int t = threadIdx.x;
    const int r0 = blockIdx.x * 8;

    {
        const float4* src = (const float4*)(x + (size_t)r0 * IN_C);
        float4* dst = (float4*)xl;
        #pragma unroll
        for (int i = 0; i < 4; i++) dst[i * 256 + t] = src[i * 256 + t];
    }
    __syncthreads();

    float acc[8];
    #pragma unroll
    for (int r = 0; r < 8; r++) acc[r] = 0.f;

    for (int c4 = 0; c4 < IN_C / 4; c4++) {
        const float w0 = Wfc[(c4 * 4 + 0) * OUT_C + t];
        const float w1 = Wfc[(c4 * 4 + 1) * OUT_C + t];
        const float w2 = Wfc[(c4 * 4 + 2) * OUT_C + t];
        const float w3 = Wfc[(c4 * 4 + 3) * OUT_C + t];
        #pragma unroll
        for (int r = 0; r < 8; r++) {
            const float4 xv = *(const float4*)&xl[r * IN_C + c4 * 4];
            acc[r] = fmaf(xv.x, w0, acc[r]);
            acc[r] = fmaf(xv.y, w1, acc[r]);
            acc[r] = fmaf(xv.z, w2, acc[r]);
            acc[r] = fmaf(xv.w, w3, acc[r]);
        }
    }
    const float bb = bfc[t];
    #pragma unroll
    for (int r = 0; r < 8; r++) acc[r] += bb;

    // rows r0..r0+7 = k-chunk u=(r0>>3)&3 of 32-k tile jt32=r0>>5, col = t
    {
        union { ushort u[8]; uint4 v; } pk;
        #pragma unroll
        for (int r = 0; r < 8; r++) pk.u[r] = f2bf(acc[r]);
        const int jt = r0 >> 5, u = (r0 >> 3) & 3;
        hb[(size_t)jt * 1024 + u * 256 + t] = pk.v;
    }

    float p1[8], p2[8];
    const float wa1 = Wa1[t], wa2 = Wa2[t];
    #pragma unroll
    for (int r = 0; r < 8; r++) { p1[r] = acc[r] * wa1; p2[r] = acc[r] * wa2; }
    #pragma unroll
    for (int off = 32; off > 0; off >>= 1) {
        #pragma unroll
        for (int r = 0; r < 8; r++) {
            p1[r] += __shfl_down(p1[r], off);
            p2[r] += __shfl_down(p2[r], off);
        }
    }
    const int wv = t >> 6, ln = t & 63;
    if (ln == 0) {
        #pragma unroll
        for (int r = 0; r < 8; r++) { red[0][r][wv] = p1[r]; red[1][r][wv] = p2[r]; }
    }
    __syncthreads();
    if (t < 16) {
        const int s = t >> 3, r = t & 7;
        float v = red[s][r][0] + red[s][r][1] + red[s][r][2] + red[s][r][3];
        v += s ? ba2[0] : ba1[0];
        if (s) s2[r0 + r] = v; else s1[r0 + r] = v;
    }
}

// ---------------- Kernel A2: smax = max(s2) ----------------
__global__ __launch_bounds__(256) void smax_kernel(const float* __restrict__ s2,
                                                   float* __restrict__ smax)
{
    __shared__ float red[4];
    float m = -1e30f;
    for (int i = threadIdx.x; i < NN; i += 256) m = fmaxf(m, s2[i]);
    #pragma unroll
    for (int off = 32; off > 0; off >>= 1) m = fmaxf(m, __shfl_down(m, off));
    if ((threadIdx.x & 63) == 0) red[threadIdx.x >> 6] = m;
    __syncthreads();
    if (threadIdx.x == 0)
        smax[0] = fmaxf(fmaxf(red[0], red[1]), fmaxf(red[2], red[3]));
}

// ---------------- Kernel P: P[row][j] = masked exp (bf16), rs[row] = row sum ----------------
// Pure streaming: 1 wave per row (8192 waves, 32/CU). adj nontemporal in,
// P nontemporal out, full-row reduce in-wave -> single rs store, no atomics.
__global__ __launch_bounds__(256, 8) void pbuild_kernel(
    const int* __restrict__ adj, const float* __restrict__ s1,
    const float* __restrict__ s2, const float* __restrict__ smaxp,
    ushort* __restrict__ P, float* __restrict__ rs)
{
    const int wave = threadIdx.x >> 6, lane = threadIdx.x & 63;
    const int row = blockIdx.x * 4 + wave;

    const float my_s1 = s1[row] * L2E;
    const float z0 = my_s1 + smaxp[0] * L2E;
    const float m_i = fmaxf(z0, 0.01f * z0);   // scaled upper bound of masked row max

    // lane covers j = c*256 + lane*4 + {0..3}, c = 0..31
    const i32x4*  arow = (const i32x4*)(adj + (size_t)row * NN) + lane;
    const float4* srow = (const float4*)s2 + lane;
    ushort* prow = P + (size_t)row * NN;
    float rsum = 0.f;

#define PPROC(AV, SV, C)                                                        \
    {                                                                           \
        const int ai[4] = {AV.x, AV.y, AV.z, AV.w};                             \
        const float si[4] = {SV.x, SV.y, SV.z, SV.w};                           \
        ushort pb[4];                                                           \
        _Pragma("unroll")                                                       \
        for (int e = 0; e < 4; e++) {                                           \
            const float zz = fmaf(si[e], L2E, my_s1);                           \
            const float ee = fmaxf(zz, 0.01f * zz);                             \
            float p = exp2f(ee - m_i);                                          \
            p = (ai[e] > 0) ? p : 0.f;                                          \
            rsum += p;                                                          \
            pb[e] = f2bf(p);                                                    \
        }                                                                       \
        u32x2 w;                                                                \
        w.x = (unsigned)pb[0] | ((unsigned)pb[1] << 16);                        \
        w.y = (unsigned)pb[2] | ((unsigned)pb[3] << 16);                        \
        __builtin_nontemporal_store(w, (u32x2*)(prow + (C) * 256 + lane * 4));  \
    }

    // 2-deep slot pipeline over c
    i32x4 Aa = __builtin_nontemporal_load(arow);
    float4 Sa = srow[0];
    i32x4 Ab = __builtin_nontemporal_load(arow + 64);
    float4 Sb = srow[64];
    #pragma unroll 1
    for (int i = 0; i < 16; ++i) {
        const int c0 = 2 * i, c1 = 2 * i + 1;
        PPROC(Aa, Sa, c0)
        {
            const int cn = (c0 + 2 < 32) ? c0 + 2 : 0;
            Aa = __builtin_nontemporal_load(arow + cn * 64);
            Sa = srow[cn * 64];
        }
        PPROC(Ab, Sb, c1)
        {
            const int cn = (c1 + 2 < 32) ? c1 + 2 : 0;
            Ab = __builtin_nontemporal_load(arow + cn * 64);
            Sb = srow[cn * 64];
        }
    }
#undef PPROC

    // wave-reduce rsum
    #pragma unroll
    for (int off = 32; off > 0; off >>= 1) rsum += __shfl_down(rsum, off);
    if (lane == 0) rs[row] = rsum;
}

// ---------------- Kernel G: out-partials = P @ h (bf16 MFMA, K-split) ----------------
// grid (256, 4): 32 rows/block, K-quarter per blockIdx.y. 4 waves = 2 row-groups
// x 2 col-halves; per wave 16x128 output (acc[8]). A 4-deep prefetch from HBM,
// B direct from L2-resident hb. No LDS, no barriers.
__global__ __launch_bounds__(256, 4) void pgemm_kernel(
    const ushort* __restrict__ P, const uint4* __restrict__ hb,
    float* __restrict__ outp, float* __restrict__ pbase)
{
    const int t = threadIdx.x;
    const int wave = t >> 6, lane = t & 63;
    const int wr = wave >> 1, ch = wave & 1;
    const int g = lane >> 4, lr = lane & 15;
    const int kq = blockIdx.y;
    const int kbase = kq * KRANGE;
    const int R0 = blockIdx.x * 32;
    const int row = R0 + wr * 16 + lr;

    // A stream: P[row][kbase + kt*32 + g*8 .. +8] -> i32x4 index kt*4
    const i32x4* arow = (const i32x4*)(P + (size_t)row * NN + kbase + g * 8);
    const uint4* hbb = hb + (size_t)(kbase >> 5) * 1024 + g * 256 + ch * 128 + lr;

    f32x4 acc[8];
    #pragma unroll
    for (int n = 0; n < 8; n++) acc[n] = (f32x4)(0.f);

    i32x4 A0 = __builtin_nontemporal_load(arow + 0);
    i32x4 A1 = __builtin_nontemporal_load(arow + 4);
    i32x4 A2 = __builtin_nontemporal_load(arow + 8);
    i32x4 A3 = __builtin_nontemporal_load(arow + 12);

#define GBODY(K, KT)                                                            \
    {                                                                           \
        const s16x8 afrag = *(const s16x8*)&A##K;                               \
        const uint4* bsrc = hbb + (size_t)(KT) * 1024;                          \
        uint4 bf[8];                                                            \
        _Pragma("unroll")                                                       \
        for (int n = 0; n < 8; n++) bf[n] = bsrc[n * 16];                       \
        _Pragma("unroll")                                                       \
        for (int n = 0; n < 8; n++)                                             \
            acc[n] = __builtin_amdgcn_mfma_f32_16x16x32_bf16(                   \
                afrag, *(const s16x8*)&bf[n], acc[n], 0, 0, 0);                 \
        const int tn = ((KT) + 4 < KRANGE / 32) ? (KT) + 4 : 0;                 \
        A##K = __builtin_nontemporal_load(arow + tn * 4);                       \
    }

    #pragma unroll 1
    for (int i = 0; i < KRANGE / 32 / 4; ++i) {
        const int tb = i * 4;
        GBODY(0, tb + 0)
        GBODY(1, tb + 1)
        GBODY(2, tb + 2)
        GBODY(3, tb + 3)
    }
#undef GBODY

    float* dst = (kq == 0) ? outp : (pbase + (size_t)(kq - 1) * ((size_t)NN * OUT_C));
    #pragma unroll
    for (int r = 0; r < 4; r++) {
        const int orow = R0 + wr * 16 + g * 4 + r;
        float* op = dst + (size_t)orow * OUT_C + ch * 128 + lr;
        #pragma unroll
        for (int n = 0; n < 8; n++)
            __builtin_nontemporal_store(acc[n][r], op + n * 16);
    }
}

// ---------------- Kernel C: combine K-split partials, normalize ----------------
__global__ __launch_bounds__(256) void combine_kernel(
    float* __restrict__ out, const float* __restrict__ pbase,
    const float* __restrict__ rs)
{
    const int row = blockIdx.x, t = threadIdx.x;
    const float inv = 1.f / rs[row];
    const size_t idx = (size_t)row * OUT_C + t;
    const size_t stride = (size_t)NN * OUT_C;
    float v = out[idx];
    #pragma unroll
    for (int q = 0; q < KSPL - 1; q++)
        v += __builtin_nontemporal_load(&pbase[idx + (size_t)q * stride]);
    out[idx] = v * inv;
}

extern "C" void kernel_launch(void* const* d_in, const int* in_sizes, int n_in,
                              void* d_out, int out_size, void* d_ws, size_t ws_size,
                              hipStream_t stream) {
    const float* x   = (const float*)d_in[0];
    const int*   adj = (const int*)d_in[1];
    const float* Wfc = (const float*)d_in[2];
    const float* bfc = (const float*)d_in[3];
    const float* Wa1 = (const float*)d_in[4];
    const float* ba1 = (const float*)d_in[5];
    const float* Wa2 = (const float*)d_in[6];
    const float* ba2 = (const float*)d_in[7];
    float* out = (float*)d_out;

    char* ws = (char*)d_ws;
    uint4* hb   = (uint4*)ws;                        // 4 MiB    [256][4][256] uint4
    float* s1   = (float*)(ws + (4u << 20));         // 32 KiB
    float* s2   = s1 + NN;                           // 32 KiB
    float* rs   = s2 + NN;                           // 32 KiB
    float* smax = rs + NN;                           // 4 B
    float* pbase = (float*)(ws + (5u << 20));        // 24 MiB   [3][8192][256] f32
    ushort* P   = (ushort*)(ws + (32u << 20));       // 128 MiB  [8192][8192] bf16

    fc_kernel<<<dim3(NN / 8), 256, 0, stream>>>(x, Wfc, bfc, Wa1, ba1, Wa2, ba2, hb, s1, s2);
    smax_kernel<<<dim3(1), 256, 0, stream>>>(s2, smax);
    pbuild_kernel<<<dim3(NN / 4), 256, 0, stream>>>(adj, s1, s2, smax, P, rs);
    pgemm_kernel<<<dim3(NN / 32, KSPL), 256, 0, stream>>>(P, hb, out, pbase);
    combine_kernel<<<dim3(NN), 256, 0, stream>>>(out, pbase, rs);
}

// Round 11
// 214.821 us; speedup vs baseline: 1.4604x; 1.4604x over previous
//
#include <hip/hip_runtime.h>
#include <hip/hip_bf16.h>

#define IN_C 512
#define OUT_C 256
#define NN 8192
#define JSPL 4
#define JRANGE (NN / JSPL)       // 2048
#define NT (JRANGE / 32)         // 64 K-steps of 32
#define L2E 1.44269504088896f

typedef __attribute__((ext_vector_type(8))) short s16x8;
typedef __attribute__((ext_vector_type(4))) float f32x4;
typedef __attribute__((ext_vector_type(4))) int i32x4;

__device__ __forceinline__ ushort f2bf(float f) {
    unsigned u = __float_as_uint(f);
    unsigned r = (u + 0x7FFF + ((u >> 16) & 1)) >> 16;
    return (ushort)r;
}

__device__ __forceinline__ void gload_lds16(const uint4* g, uint4* l) {
    __builtin_amdgcn_global_load_lds(
        (const __attribute__((address_space(1))) unsigned int*)g,
        (__attribute__((address_space(3))) unsigned int*)l, 16, 0, 0);
}

// ---------------- Kernel A: h = x@W_fc + b_fc (fp32); store h bf16 in k-chunk-major
// granules hb[kt][g][col] (uint4 = 8 bf16, k = kt*32 + g*8 + e); also s1, s2 ----------------
__global__ __launch_bounds__(256) void fc_kernel(
    const float* __restrict__ x, const float* __restrict__ Wfc,
    const float* __restrict__ bfc, const float* __restrict__ Wa1,
    const float* __restrict__ ba1, const float* __restrict__ Wa2,
    const float* __restrict__ ba2,
    uint4* __restrict__ hb,     // [NN/32][4][256] uint4
    float* __restrict__ s1, float* __restrict__ s2)
{
    __shared__ float xl[8 * IN_C];          // 16 KB
    __shared__ float red[2][8][4];
    const int t = threadIdx.x;
    const int r0 = blockIdx.x * 8;

    {
        const float4* src = (const float4*)(x + (size_t)r0 * IN_C);
        float4* dst = (float4*)xl;
        #pragma unroll
        for (int i = 0; i < 4; i++) dst[i * 256 + t] = src[i * 256 + t];
    }
    __syncthreads();

    float acc[8];
    #pragma unroll
    for (int r = 0; r < 8; r++) acc[r] = 0.f;

    for (int c4 = 0; c4 < IN_C / 4; c4++) {
        const float w0 = Wfc[(c4 * 4 + 0) * OUT_C + t];
        const float w1 = Wfc[(c4 * 4 + 1) * OUT_C + t];
        const float w2 = Wfc[(c4 * 4 + 2) * OUT_C + t];
        const float w3 = Wfc[(c4 * 4 + 3) * OUT_C + t];
        #pragma unroll
        for (int r = 0; r < 8; r++) {
            const float4 xv = *(const float4*)&xl[r * IN_C + c4 * 4];
            acc[r] = fmaf(xv.x, w0, acc[r]);
            acc[r] = fmaf(xv.y, w1, acc[r]);
            acc[r] = fmaf(xv.z, w2, acc[r]);
            acc[r] = fmaf(xv.w, w3, acc[r]);
        }
    }
    const float bb = bfc[t];
    #pragma unroll
    for (int r = 0; r < 8; r++) acc[r] += bb;

    {
        union { ushort u[8]; uint4 v; } pk;
        #pragma unroll
        for (int r = 0; r < 8; r++) pk.u[r] = f2bf(acc[r]);
        const int jt = r0 >> 5, u = (r0 >> 3) & 3;
        hb[(size_t)jt * 1024 + u * 256 + t] = pk.v;
    }

    float p1[8], p2[8];
    const float wa1 = Wa1[t], wa2 = Wa2[t];
    #pragma unroll
    for (int r = 0; r < 8; r++) { p1[r] = acc[r] * wa1; p2[r] = acc[r] * wa2; }
    #pragma unroll
    for (int off = 32; off > 0; off >>= 1) {
        #pragma unroll
        for (int r = 0; r < 8; r++) {
            p1[r] += __shfl_down(p1[r], off);
            p2[r] += __shfl_down(p2[r], off);
        }
    }
    const int wv = t >> 6, ln = t & 63;
    if (ln == 0) {
        #pragma unroll
        for (int r = 0; r < 8; r++) { red[0][r][wv] = p1[r]; red[1][r][wv] = p2[r]; }
    }
    __syncthreads();
    if (t < 16) {
        const int s = t >> 3, r = t & 7;
        float v = red[s][r][0] + red[s][r][1] + red[s][r][2] + red[s][r][3];
        v += s ? ba2[0] : ba1[0];
        if (s) s2[r0 + r] = v; else s1[r0 + r] = v;
    }
}

// ---------------- Kernel A2: smax = max(s2) ----------------
__global__ __launch_bounds__(256) void smax_kernel(const float* __restrict__ s2,
                                                   float* __restrict__ smax)
{
    __shared__ float red[4];
    float m = -1e30f;
    for (int i = threadIdx.x; i < NN; i += 256) m = fmaxf(m, s2[i]);
    #pragma unroll
    for (int off = 32; off > 0; off >>= 1) m = fmaxf(m, __shfl_down(m, off));
    if ((threadIdx.x & 63) == 0) red[threadIdx.x >> 6] = m;
    __syncthreads();
    if (threadIdx.x == 0)
        smax[0] = fmaxf(fmaxf(red[0], red[1]), fmaxf(red[2], red[3]));
}

// ---------------- Kernel B: fused masked-softmax-numerator @ h, m97 skeleton ----------------
// grid (128, 4), 512 threads = 8 waves (4 row-groups wr x 2 col-halves ch).
// Block tile: 64 rows x 256 cols, K-step 32, J-quarter per blockIdx.y.
// B (h) double-buffered in LDS via global_load_lds (lgkmcnt domain -> no vmcnt
// drain on consume); adj per-lane direct, 4-deep register rotation (vmcnt only
// drained at the per-step barrier). One __syncthreads per K-step.
__global__ __launch_bounds__(512, 4) void attn_kernel(
    const int* __restrict__ adj, const uint4* __restrict__ hb,
    const float* __restrict__ s1, const float* __restrict__ s2,
    const float* __restrict__ smaxp, float* __restrict__ outp,
    float* __restrict__ pbase, float* __restrict__ rs)
{
    __shared__ float s2l[JRANGE];          // 8 KB (pre-scaled by log2e)
    __shared__ uint4 hbuf[2][1024];        // 2 x 16 KB B tiles [g][col] granules

    const int t = threadIdx.x;
    const int wave = t >> 6, lane = t & 63;
    const int wr = wave >> 1, ch = wave & 1;
    const int g = lane >> 4, lr = lane & 15;
    const int jq = blockIdx.y;
    const int Jbase = jq * JRANGE;
    const int R0 = blockIdx.x * 64;
    const int row = R0 + wr * 16 + lr;

    // stage s2 slice (x log2e): 2048 floats / 512 threads = 1 float4 each
    {
        const float4 v = ((const float4*)(s2 + Jbase))[t];
        ((float4*)s2l)[t] = make_float4(v.x * L2E, v.y * L2E, v.z * L2E, v.w * L2E);
    }

    const float my_s1 = s1[row] * L2E;
    const float z0 = my_s1 + smaxp[0] * L2E;
    const float m_i = fmaxf(z0, 0.01f * z0);   // scaled upper bound of masked row max

    const uint4* hb_base = hb + (size_t)(Jbase >> 5) * 1024;
    // adj granule stream: index (tt*8 + g*2 + h)
    const i32x4* aptr = (const i32x4*)(adj + (size_t)row * NN + Jbase) + g * 2;

    f32x4 acc[8];
    #pragma unroll
    for (int n = 0; n < 8; n++) acc[n] = (f32x4)(0.f);
    float rsum = 0.f;

    // prologue: stage B tile 0, prefetch adj tiles 0..3 (4-deep, named slots)
    gload_lds16(hb_base + t, &hbuf[0][t]);
    gload_lds16(hb_base + 512 + t, &hbuf[0][512 + t]);
    i32x4 A0a = __builtin_nontemporal_load(aptr + 0);
    i32x4 A0b = __builtin_nontemporal_load(aptr + 1);
    i32x4 A1a = __builtin_nontemporal_load(aptr + 8);
    i32x4 A1b = __builtin_nontemporal_load(aptr + 9);
    i32x4 A2a = __builtin_nontemporal_load(aptr + 16);
    i32x4 A2b = __builtin_nontemporal_load(aptr + 17);
    i32x4 A3a = __builtin_nontemporal_load(aptr + 24);
    i32x4 A3b = __builtin_nontemporal_load(aptr + 25);
    __syncthreads();

#define BODY(K, TT)                                                              \
    {                                                                            \
        const int cur = (TT) & 1;                                                \
        if ((TT) + 1 < NT) {                                                     \
            const uint4* gs = hb_base + (size_t)((TT) + 1) * 1024;               \
            gload_lds16(gs + t, &hbuf[cur ^ 1][t]);                              \
            gload_lds16(gs + 512 + t, &hbuf[cur ^ 1][512 + t]);                  \
        }                                                                        \
        const int av[8] = {A##K##a.x, A##K##a.y, A##K##a.z, A##K##a.w,           \
                           A##K##b.x, A##K##b.y, A##K##b.z, A##K##b.w};          \
        const int tn = ((TT) + 4 < NT) ? (TT) + 4 : 0;                           \
        A##K##a = __builtin_nontemporal_load(aptr + tn * 8);                     \
        A##K##b = __builtin_nontemporal_load(aptr + tn * 8 + 1);                 \
        const int j0 = (TT) * 32 + g * 8;                                        \
        const float4 sva = *(const float4*)(s2l + j0);                           \
        const float4 svb = *(const float4*)(s2l + j0 + 4);                       \
        const float sv[8] = {sva.x, sva.y, sva.z, sva.w, svb.x, svb.y, svb.z, svb.w}; \
        union { ushort u[8]; s16x8 v; } pk;                                      \
        _Pragma("unroll")                                                        \
        for (int e = 0; e < 8; e++) {                                            \
            const float zz = my_s1 + sv[e];                                      \
            const float ee = fmaxf(zz, 0.01f * zz);                              \
            float p = exp2f(ee - m_i);                                           \
            p = (av[e] > 0) ? p : 0.f;                                           \
            rsum += p;                                                           \
            pk.u[e] = f2bf(p);                                                   \
        }                                                                        \
        const s16x8 afrag = pk.v;                                                \
        _Pragma("unroll")                                                        \
        for (int n = 0; n < 8; n++) {                                            \
            const s16x8 bfrag = *(const s16x8*)&hbuf[cur][g * 256 + ch * 128 + n * 16 + lr]; \
            acc[n] = __builtin_amdgcn_mfma_f32_16x16x32_bf16(afrag, bfrag, acc[n], 0, 0, 0); \
        }                                                                        \
        __syncthreads();                                                         \
    }

    #pragma unroll 1
    for (int i = 0; i < NT / 4; ++i) {
        const int tb = i * 4;
        BODY(0, tb + 0)
        BODY(1, tb + 1)
        BODY(2, tb + 2)
        BODY(3, tb + 3)
    }
#undef BODY

    // row-sum reduce across the 4 k-groups; one writer per row (ch==0)
    rsum += __shfl_xor(rsum, 16);
    rsum += __shfl_xor(rsum, 32);
    if (ch == 0 && g == 0) rs[(size_t)jq * NN + row] = rsum;

    float* dst = (jq == 0) ? outp : (pbase + (size_t)(jq - 1) * ((size_t)NN * OUT_C));
    #pragma unroll
    for (int r = 0; r < 4; r++) {
        const int orow = R0 + wr * 16 + g * 4 + r;
        float* op = dst + (size_t)orow * OUT_C + ch * 128 + lr;
        #pragma unroll
        for (int n = 0; n < 8; n++)
            __builtin_nontemporal_store(acc[n][r], op + n * 16);
    }
}

// ---------------- Kernel C: combine partials, normalize ----------------
__global__ __launch_bounds__(256) void combine_kernel(
    float* __restrict__ out, const float* __restrict__ pbase,
    const float* __restrict__ rs)
{
    const int row = blockIdx.x, t = threadIdx.x;
    float rsum = 0.f;
    #pragma unroll
    for (int q = 0; q < JSPL; q++) rsum += rs[(size_t)q * NN + row];
    const float inv = 1.f / rsum;
    const size_t idx = (size_t)row * OUT_C + t;
    const size_t stride = (size_t)NN * OUT_C;
    float v = out[idx];
    #pragma unroll
    for (int q = 0; q < JSPL - 1; q++)
        v += __builtin_nontemporal_load(&pbase[idx + (size_t)q * stride]);
    out[idx] = v * inv;
}

extern "C" void kernel_launch(void* const* d_in, const int* in_sizes, int n_in,
                              void* d_out, int out_size, void* d_ws, size_t ws_size,
                              hipStream_t stream) {
    const float* x   = (const float*)d_in[0];
    const int*   adj = (const int*)d_in[1];
    const float* Wfc = (const float*)d_in[2];
    const float* bfc = (const float*)d_in[3];
    const float* Wa1 = (const float*)d_in[4];
    const float* ba1 = (const float*)d_in[5];
    const float* Wa2 = (const float*)d_in[6];
    const float* ba2 = (const float*)d_in[7];
    float* out = (float*)d_out;

    char* ws = (char*)d_ws;
    uint4* hb   = (uint4*)ws;                        // 4 MiB   [256][4][256] uint4
    float* s1   = (float*)(ws + (4u << 20));         // 32 KiB
    float* s2   = s1 + NN;                           // 32 KiB
    float* rs   = s2 + NN;                           // 128 KiB [4][8192]
    float* smax = rs + JSPL * NN;                    // 4 B
    float* pbase = (float*)(ws + (5u << 20));        // 24 MiB  [3][8192][256] f32

    fc_kernel<<<dim3(NN / 8), 256, 0, stream>>>(x, Wfc, bfc, Wa1, ba1, Wa2, ba2, hb, s1, s2);
    smax_kernel<<<dim3(1), 256, 0, stream>>>(s2, smax);
    attn_kernel<<<dim3(NN / 64, JSPL), 512, 0, stream>>>(adj, hb, s1, s2, smax, out, pbase, rs);
    combine_kernel<<<dim3(NN), 256, 0, stream>>>(out, pbase, rs);
}